// Round 12
// baseline (903.366 us; speedup 1.0000x reference)
//
#include <hip/hip_runtime.h>
#include <hip/hip_bf16.h>

typedef __hip_bfloat16 bf16;
typedef __attribute__((ext_vector_type(8))) short short8;   // 8 x bf16 (4 VGPRs)
typedef __attribute__((ext_vector_type(4))) float f32x4;

#define Hdim 512
#define Bdim 512
#define Tdim 64
#define Fdim 64
#define NC   4

__device__ __forceinline__ float sigmoidf_(float x){ return 1.f/(1.f + __expf(-x)); }
__device__ __forceinline__ float tanhf_(float x){
  float t = __expf(-2.f*fabsf(x));
  float r = (1.f - t)/(1.f + t);
  return copysignf(r, x);
}
__device__ __forceinline__ float bf2f_(short u){
  return __uint_as_float(((unsigned)(unsigned short)u) << 16);
}
__device__ __forceinline__ short f2bf_(float f){
  bf16 b = (bf16)f;
  return *(short*)&b;
}

// ---------------- fp32 -> bf16 pack (fc_in_W only) ----------------
__global__ __launch_bounds__(256) void pack_kernel(const float* __restrict__ src,
                                                   bf16* __restrict__ dst, int n){
  int idx = (blockIdx.x*256 + threadIdx.x)*4;
  if (idx < n){
    float4 v = *(const float4*)(src + idx);
    dst[idx+0] = (bf16)v.x;
    dst[idx+1] = (bf16)v.y;
    dst[idx+2] = (bf16)v.z;
    dst[idx+3] = (bf16)v.w;
  }
}

// ---------------- transpose data [B][F][T] fp32 -> dataT [T][B][F] bf16 ----------------
__global__ __launch_bounds__(256) void transpose_kernel(const float* __restrict__ data,
                                                        bf16* __restrict__ dataT){
  __shared__ bf16 tile[64*65];
  int b = blockIdx.x;
  int tid = threadIdx.x;
  for (int i = 0; i < 16; ++i){
    int idx = tid + i*256;
    int f = idx >> 6, t = idx & 63;
    tile[f*65 + t] = (bf16)data[(b*64 + f)*64 + t];
  }
  __syncthreads();
  for (int i = 0; i < 16; ++i){
    int idx = tid + i*256;
    int t = idx >> 6, f = idx & 63;
    dataT[(t*Bdim + b)*64 + f] = tile[f*65 + t];
  }
}

// ---------------- init: h(-1) bf16 shadow in OWNER-MAJOR layout [k][bt][j][b][32] ----
__global__ __launch_bounds__(256) void init_kernel(const float* __restrict__ init_h,
                            bf16* __restrict__ h_b1, unsigned* __restrict__ flags){
  int idx = blockIdx.x*256 + threadIdx.x;          // 0 .. 4*512*512-1
  int k = idx >> 18;
  int rem = idx & 262143;                          // b_glob*512 + o
  int bg = rem >> 9;
  int o  = rem & 511;
  int dst = ((k*2 + (bg >> 8))*16 + (o >> 5))*8192 + (bg & 255)*32 + (o & 31);
  h_b1[dst] = (bf16)init_h[rem];
  if (idx < 512) flags[idx] = 0u;                  // flags[8][32] + xslot[8][32]
}

// ---------------- input projection: x_seq[s][k][b][h] = relu(dataT[src_t] @ fc_in_W[k]^T + b)
__global__ __launch_bounds__(256) void proj_kernel(const bf16* __restrict__ dataT,
    const bf16* __restrict__ fc_in_W, const float* __restrict__ fc_in_b,
    bf16* __restrict__ x_seq){
  __shared__ short ldsA[64*72];
  __shared__ short ldsW[128*72];
  int blk = blockIdx.x;
  int s  = blk >> 7;
  int k  = (blk >> 5) & 3;
  int bt = (blk >> 2) & 7;
  int on = blk & 3;
  int tid = threadIdx.x;
  int lane = tid & 63, wid = tid >> 6;
  int quad = lane >> 4, l16 = lane & 15;
  int src_t = (k < 2) ? s : (Tdim - 1 - s);

  const short* Ag = (const short*)(dataT + (src_t*Bdim + bt*64)*Fdim);
  #pragma unroll
  for (int i = 0; i < 2; ++i){
    int c = tid + i*256; int r = c >> 3, off = c & 7;
    *(int4*)(&ldsA[r*72 + off*8]) = *(const int4*)(&Ag[r*64 + off*8]);
  }
  const short* Wg = (const short*)(fc_in_W + (k*Hdim + on*128)*Fdim);
  #pragma unroll
  for (int i = 0; i < 4; ++i){
    int c = tid + i*256; int r = c >> 3, off = c & 7;
    *(int4*)(&ldsW[r*72 + off*8]) = *(const int4*)(&Wg[r*64 + off*8]);
  }
  __syncthreads();

  f32x4 acc[2][4];
  #pragma unroll
  for (int nt=0; nt<2; ++nt)
    #pragma unroll
    for (int rb=0; rb<4; ++rb) acc[nt][rb] = (f32x4){0.f,0.f,0.f,0.f};

  #pragma unroll
  for (int kk = 0; kk < 2; ++kk){
    int io = kk*32 + quad*8;
    short8 a[4];
    #pragma unroll
    for (int rb=0; rb<4; ++rb) a[rb] = *(const short8*)(&ldsA[(rb*16+l16)*72 + io]);
    #pragma unroll
    for (int nt=0; nt<2; ++nt){
      short8 bw = *(const short8*)(&ldsW[(wid*32 + nt*16 + l16)*72 + io]);
      #pragma unroll
      for (int rb=0; rb<4; ++rb)
        acc[nt][rb] = __builtin_amdgcn_mfma_f32_16x16x32_bf16(a[rb], bw, acc[nt][rb], 0,0,0);
    }
  }

  #pragma unroll
  for (int nt=0; nt<2; ++nt){
    int o = on*128 + wid*32 + nt*16 + l16;
    float bias = fc_in_b[k*Hdim + o];
    #pragma unroll
    for (int rb=0; rb<4; ++rb){
      #pragma unroll
      for (int reg=0; reg<4; ++reg){
        int b = bt*64 + rb*16 + quad*4 + reg;
        float v = acc[nt][rb][reg] + bias;
        v = v > 0.f ? v : 0.f;
        x_seq[((size_t)(s*NC + k)*Bdim + b)*Hdim + o] = (bf16)v;
      }
    }
  }
}

// ---------------- persistent GRU, producer/consumer split, PAIRWISE sync ----------------
// r12: dependency-exact sync. gi block j: producer j -> consumer j ONLY (1 flag).
// gi ring slot WAR: producer j waits consumer j ONLY (1 flag). h chunk c == consumer
// c's owner-major 16KB block -> per-wave ready-order DATAFLOW over the 16 consumer
// flags (r9 machinery, now 1:1 with the layout). The three all-to-all rendezvous
// per step (r11's residual ~8 us of skew+poll) collapse to pairwise waits absorbed
// behind GEMM work. No entry barriers — every wait is per-wave.
__global__ __launch_bounds__(512) void rnn_kernel(
    const bf16* __restrict__ x_seq, const float* __restrict__ init_h,
    bf16* __restrict__ h_b0, bf16* __restrict__ h_b1,
    const float* __restrict__ Wih, const float* __restrict__ Whh,
    const float* __restrict__ bih, const float* __restrict__ bhh,
    const float* __restrict__ fc_out_W,
    bf16* __restrict__ gi, float* __restrict__ part,
    unsigned* __restrict__ flags, unsigned* __restrict__ xslot)
{
  __shared__ short wlds[3*2*16*512];   // 96 KB: [plane3][nt2][kc16][lane64] x 8 bf16
  __shared__ int sslot;

  int tid = threadIdx.x;
  int lane = tid & 63, wid = tid >> 6;          // wid 0..7
  int quad = lane >> 4, l16 = lane & 15;

  // ---- physical-XCD self-assignment ----
  unsigned xcc;
  asm volatile("s_getreg_b32 %0, hwreg(HW_REG_XCC_ID)" : "=s"(xcc));
  xcc &= 7u;
  if (tid == 0)
    sslot = (int)__hip_atomic_fetch_add(&xslot[xcc*32], 1u,
                __ATOMIC_RELAXED, __HIP_MEMORY_SCOPE_WORKGROUP);
  __syncthreads();
  int grp = (int)xcc;
  int k   = grp >> 1;
  int bt  = grp & 1;
  int slot = sslot & 31;               // 0..31 unique in XCD (1 block/CU pigeonhole)
  int producer = (slot < 16);
  int j    = slot & 15;                // o-tile index within role (pair id)
  int obase = j*32;
  int rot  = j;                        // phase stagger
  unsigned* gflags = flags + grp*32;   // [0..15]=producers, [16..31]=consumers

  // ---- single-side weights -> LDS once, fp32->bf16, B-fragment lane order ----
  const float* Wsrc = producer ? Wih : Whh;
  for (int i = tid; i < 3*2*16*64; i += 512){
    int plane = i >> 11;
    int rem   = i & 2047;
    int nt    = rem >> 10;
    int rem2  = rem & 1023;
    int kc    = rem2 >> 6;
    int ln    = rem2 & 63;
    int ll16  = ln & 15, lq = ln >> 4;
    const float* srcp = Wsrc +
        ((size_t)(k*3 + plane)*Hdim + obase + nt*16 + ll16)*Hdim + kc*32 + lq*8;
    float4 f0 = *(const float4*)srcp;
    float4 f1 = *(const float4*)(srcp + 4);
    short8 pk;
    pk[0]=f2bf_(f0.x); pk[1]=f2bf_(f0.y); pk[2]=f2bf_(f0.z); pk[3]=f2bf_(f0.w);
    pk[4]=f2bf_(f1.x); pk[5]=f2bf_(f1.y); pk[6]=f2bf_(f1.z); pk[7]=f2bf_(f1.w);
    *(int4*)(&wlds[i*8]) = *(int4*)&pk;
  }

  // producer GEMM over x (row stride 512): 16 K32 chunks, phase rot
  #define GEMM32X(ABASE) do {                                                   \
    const short* ap0_ = (ABASE) + (wid*32 + l16)*Hdim + quad*8;                 \
    const short* ap1_ = ap0_ + 16*Hdim;                                         \
    short8 ab_[4][2];                                                           \
    _Pragma("unroll")                                                           \
    for (int d=0; d<4; ++d){                                                    \
      int c_ = (d + rot) & 15;                                                  \
      ab_[d][0] = *(const short8*)(ap0_ + c_*32);                               \
      ab_[d][1] = *(const short8*)(ap1_ + c_*32);                               \
    }                                                                           \
    short8 bb_[2][6];                                                           \
    _Pragma("unroll")                                                           \
    for (int p=0; p<6; ++p)                                                     \
      bb_[0][p] = *(const short8*)(&wlds[((p*16 + rot)<<9) + (lane<<3)]);       \
    _Pragma("unroll")                                                           \
    for (int kc=0; kc<16; ++kc){                                                \
      short8 a0_ = ab_[kc&3][0], a1_ = ab_[kc&3][1];                            \
      if (kc < 12){                                                             \
        int c_ = (kc + 4 + rot) & 15;                                           \
        ab_[kc&3][0] = *(const short8*)(ap0_ + c_*32);                          \
        ab_[kc&3][1] = *(const short8*)(ap1_ + c_*32);                          \
      }                                                                         \
      if (kc < 15){                                                             \
        int c_ = (kc + 1 + rot) & 15;                                           \
        _Pragma("unroll")                                                       \
        for (int p=0; p<6; ++p)                                                 \
          bb_[(kc+1)&1][p] = *(const short8*)(&wlds[((p*16 + c_)<<9) + (lane<<3)]); \
      }                                                                         \
      _Pragma("unroll")                                                         \
      for (int g=0; g<3; ++g){                                                  \
        _Pragma("unroll")                                                       \
        for (int nt=0; nt<2; ++nt){                                             \
          short8 bw_ = bb_[kc&1][g*2+nt];                                       \
          acc[g][nt][0] = __builtin_amdgcn_mfma_f32_16x16x32_bf16(a0_, bw_, acc[g][nt][0], 0,0,0); \
          acc[g][nt][1] = __builtin_amdgcn_mfma_f32_16x16x32_bf16(a1_, bw_, acc[g][nt][1], 0,0,0); \
        }                                                                       \
      }                                                                         \
    }                                                                           \
  } while(0)

  // single-flag per-wave wait (wave-uniform address -> 1 L2 request, broadcast)
  #define WAITONE(fidx, thr) do {                                               \
    int g_ = 0;                                                                 \
    while (__hip_atomic_load(&gflags[fidx], __ATOMIC_RELAXED,                   \
                             __HIP_MEMORY_SCOPE_AGENT) < (unsigned)(thr)){      \
      __builtin_amdgcn_s_sleep(1);                                              \
      if (++g_ > 4000000) break;                                                \
    }                                                                           \
    __asm__ __volatile__("" ::: "memory");                                      \
  } while(0)

  if (producer){
    __syncthreads();   // LDS fill complete
    for (int s = 0; s < 64; ++s){
      f32x4 acc[3][2][2];
      #pragma unroll
      for (int g=0; g<3; ++g)
        #pragma unroll
        for (int nt=0; nt<2; ++nt){
          acc[g][nt][0] = (f32x4){0.f,0.f,0.f,0.f};
          acc[g][nt][1] = (f32x4){0.f,0.f,0.f,0.f};
        }
      // ring slot s&1 WAR: only pair consumer j reads gi block j
      if (s >= 2) WAITONE(16 + j, s - 1);
      const short* x_base = (const short*)(x_seq + ((size_t)(s*NC + k)*Bdim + bt*256)*Hdim);
      GEMM32X(x_base);
      bf16* gb = gi + ((size_t)(((s&1)*8 + grp)*16 + j))*24576;
      #pragma unroll
      for (int g=0; g<3; ++g){
        #pragma unroll
        for (int nt=0; nt<2; ++nt){
          short8 pk;
          #pragma unroll
          for (int rb=0; rb<2; ++rb)
            #pragma unroll
            for (int reg=0; reg<4; ++reg)
              pk[rb*4+reg] = f2bf_(acc[g][nt][rb][reg]);
          *(int4*)(gb + ((g*2+nt)*512 + wid*64 + lane)*8) = *(int4*)&pk;
        }
      }
      __syncthreads();                     // drains vmcnt(0): gi visible in local L2
      if (tid == 0)
        __hip_atomic_fetch_add(&gflags[j], 1u,
                               __ATOMIC_RELAXED, __HIP_MEMORY_SCOPE_AGENT);
    }
  } else {
    // ---- consumer: biases, output weights, fp32 h state in registers ----
    int o0 = obase + l16, o1 = o0 + 16;
    float br0  = bih[k*3*Hdim + o0] + bhh[k*3*Hdim + o0];
    float br1  = bih[k*3*Hdim + o1] + bhh[k*3*Hdim + o1];
    float bz0  = bih[k*3*Hdim + Hdim + o0] + bhh[k*3*Hdim + Hdim + o0];
    float bz1  = bih[k*3*Hdim + Hdim + o1] + bhh[k*3*Hdim + Hdim + o1];
    float bnx0 = bih[k*3*Hdim + 2*Hdim + o0];
    float bnx1 = bih[k*3*Hdim + 2*Hdim + o1];
    float bnh0 = bhh[k*3*Hdim + 2*Hdim + o0];
    float bnh1 = bhh[k*3*Hdim + 2*Hdim + o1];
    float wout0 = fc_out_W[(k & 1)*Hdim + o0];
    float wout1 = fc_out_W[(k & 1)*Hdim + o1];

    float hk[2][2][4];   // [nt][rb][reg]
    #pragma unroll
    for (int nt=0; nt<2; ++nt)
      #pragma unroll
      for (int rb=0; rb<2; ++rb)
        #pragma unroll
        for (int reg=0; reg<4; ++reg)
          hk[nt][rb][reg] =
            init_h[(bt*256 + wid*32 + rb*16 + quad*4 + reg)*Hdim + obase + nt*16 + l16];

    __syncthreads();   // LDS fill complete

    const int hgrp = (k*2 + bt)*16;    // h block base index for this group

    // h-chunk load / mfma (owner-major: chunk c at offset c*8192 shorts)
    #define HLOADC(c, A0, A1, B) do {                                           \
      A0 = *(const short8*)(hp0 + (size_t)(c)*8192);                            \
      A1 = *(const short8*)(hp1 + (size_t)(c)*8192);                            \
      _Pragma("unroll")                                                         \
      for (int p=0; p<6; ++p)                                                   \
        B[p] = *(const short8*)(&wlds[((p*16 + (c))<<9) + (lane<<3)]);          \
    } while(0)
    #define HMFMAC(A0, A1, B) do {                                              \
      _Pragma("unroll")                                                         \
      for (int g=0; g<3; ++g){                                                  \
        _Pragma("unroll")                                                       \
        for (int nt=0; nt<2; ++nt){                                             \
          acc[g][nt][0] = __builtin_amdgcn_mfma_f32_16x16x32_bf16(A0, B[g*2+nt], acc[g][nt][0], 0,0,0); \
          acc[g][nt][1] = __builtin_amdgcn_mfma_f32_16x16x32_bf16(A1, B[g*2+nt], acc[g][nt][1], 0,0,0); \
        }                                                                       \
      }                                                                         \
    } while(0)
    // per-wave ready-order pick over the 16 consumer flags (chunk c <-> flag 16+c)
    #define PICKH(cvar) do {                                                    \
      int g_ = 0;                                                               \
      while (!avail){                                                           \
        unsigned v_ = 0xFFFFFFFFu;                                              \
        if (lane < 16)                                                          \
          v_ = __hip_atomic_load(&gflags[16 + lane], __ATOMIC_RELAXED,          \
                                 __HIP_MEMORY_SCOPE_AGENT);                     \
        unsigned r_ = (unsigned)__ballot(v_ >= (unsigned)s) & 0xFFFFu;          \
        avail = r_ & ~done;                                                     \
        if (!avail){                                                            \
          __builtin_amdgcn_s_sleep(1);                                          \
          if (++g_ > 4000000) avail = 0xFFFFu & ~done;                          \
        }                                                                       \
      }                                                                         \
      unsigned hi_ = avail >> rot;                                              \
      cvar = hi_ ? rot + __builtin_ctz(hi_) : __builtin_ctz(avail);             \
      avail &= ~(1u << cvar);                                                   \
      done  |= (1u << cvar);                                                    \
      __asm__ __volatile__("" ::: "memory");                                    \
    } while(0)

    for (int s = 0; s < 64; ++s){
      const bf16* h_in  = (s & 1) ? h_b0 : h_b1;
      bf16*       h_out = (s & 1) ? h_b1 : h_b0;

      f32x4 acc[3][2][2];
      #pragma unroll
      for (int g=0; g<3; ++g)
        #pragma unroll
        for (int nt=0; nt<2; ++nt){
          acc[g][nt][0] = (f32x4){0.f,0.f,0.f,0.f};
          acc[g][nt][1] = (f32x4){0.f,0.f,0.f,0.f};
        }

      // gi[s] ready: pair producer only (per-wave, single flag)
      WAITONE(j, s + 1);

      // gi prefetch first (latency hides under the h-GEMM)
      const bf16* gb = gi + ((size_t)(((s&1)*8 + grp)*16 + j))*24576;
      short8 gv[6];
      #pragma unroll
      for (int p=0; p<6; ++p){
        int4 t = *(const int4*)(gb + (p*512 + wid*64 + lane)*8);
        gv[p] = *(short8*)&t;
      }

      // h-GEMM: ready-order chunk dataflow, depth-1 pipeline
      const short* hp0 = (const short*)h_in + (size_t)hgrp*8192 + (wid*32 + l16)*32 + quad*8;
      const short* hp1 = hp0 + 16*32;
      {
        unsigned done = 0;
        unsigned avail = (s == 0) ? 0xFFFFu : 0u;
        int c;
        short8 A0c, A1c, Bc[6], A0n, A1n, Bn[6];
        PICKH(c);
        HLOADC(c, A0c, A1c, Bc);
        #pragma unroll 1
        for (int it = 1; it < 16; ++it){
          PICKH(c);
          HLOADC(c, A0n, A1n, Bn);
          HMFMAC(A0c, A1c, Bc);
          A0c = A0n; A1c = A1n;
          #pragma unroll
          for (int p=0; p<6; ++p) Bc[p] = Bn[p];
        }
        HMFMAC(A0c, A1c, Bc);
      }

      // ---- epilogue: gates, register h update, owner-contiguous h store, nt part ----
      int tmap = (k < 2) ? s : (Tdim - 1 - s);
      bf16* hob = h_out + (size_t)(hgrp + j)*8192;
      #pragma unroll
      for (int rb = 0; rb < 2; ++rb){
        #pragma unroll
        for (int reg = 0; reg < 4; ++reg){
          int bl = wid*32 + rb*16 + quad*4 + reg;     // local b row
          float v = 0.f;
          #pragma unroll
          for (int nt = 0; nt < 2; ++nt){
            float gir = bf2f_(gv[0*2+nt][rb*4+reg]);
            float giz = bf2f_(gv[1*2+nt][rb*4+reg]);
            float gin = bf2f_(gv[2*2+nt][rb*4+reg]);
            float br  = nt ? br1 : br0,  bz = nt ? bz1 : bz0;
            float bnx = nt ? bnx1 : bnx0, bnh = nt ? bnh1 : bnh0;
            float r = sigmoidf_(gir + acc[0][nt][rb][reg] + br);
            float z = sigmoidf_(giz + acc[1][nt][rb][reg] + bz);
            float n = tanhf_(gin + bnx + r*(acc[2][nt][rb][reg] + bnh));
            float hn = (1.f - z)*n + z*hk[nt][rb][reg];
            hk[nt][rb][reg] = hn;
            hob[bl*32 + nt*16 + l16] = (bf16)hn;
            v += hn * (nt ? wout1 : wout0);
          }
          v += __shfl_xor(v, 1, 64);
          v += __shfl_xor(v, 2, 64);
          v += __shfl_xor(v, 4, 64);
          v += __shfl_xor(v, 8, 64);
          if (l16 == 0)
            __builtin_nontemporal_store(v,
              &part[((size_t)(k*Tdim + tmap)*16 + j)*Bdim + bt*256 + bl]);
        }
      }

      __syncthreads();                   // drains vmcnt(0): h in local L2
      if (tid == 0)
        __hip_atomic_fetch_add(&gflags[16 + j], 1u,
                               __ATOMIC_RELAXED, __HIP_MEMORY_SCOPE_AGENT);
    }
    #undef HLOADC
    #undef HMFMAC
    #undef PICKH
  }
  #undef GEMM32X
  #undef WAITONE
}

// ---------------- out[head][b][t] = bias + sum over {head,head+2} x 16 j-partials ----
__global__ __launch_bounds__(256) void finalize_kernel(const float* __restrict__ part,
                                const float* __restrict__ fc_out_b, float* __restrict__ out){
  int idx = blockIdx.x*256 + threadIdx.x;  // 0..65535
  int head = idx >> 15;
  int b = (idx >> 6) & 511;
  int t = idx & 63;
  float v = fc_out_b[head];
  #pragma unroll
  for (int kk = 0; kk < 2; ++kk){
    const float* p = part + (size_t)((head + kk*2)*Tdim + t)*16*Bdim + b;
    #pragma unroll
    for (int jj = 0; jj < 16; ++jj)
      v += p[jj*Bdim];
  }
  out[idx] = v;
}

extern "C" void kernel_launch(void* const* d_in, const int* in_sizes, int n_in,
                              void* d_out, int out_size, void* d_ws, size_t ws_size,
                              hipStream_t stream){
  (void)in_sizes; (void)n_in; (void)out_size; (void)ws_size;
  const float* data     = (const float*)d_in[0];
  const float* init_h   = (const float*)d_in[1];
  const float* fc_in_W  = (const float*)d_in[2];
  const float* fc_in_b  = (const float*)d_in[3];
  const float* Wih      = (const float*)d_in[4];
  const float* Whh      = (const float*)d_in[5];
  const float* bih      = (const float*)d_in[6];
  const float* bhh      = (const float*)d_in[7];
  const float* fc_out_W = (const float*)d_in[8];
  const float* fc_out_b = (const float*)d_in[9];
  float* out = (float*)d_out;

  char* ws = (char*)d_ws;
  bf16*  x_seq   = (bf16*)ws;                     // [T][K][B][H] bf16 : 134217728 B
  bf16*  h_b0    = (bf16*)(ws + 134217728);       // [k][bt][j][b][32] :  2097152 B
  bf16*  h_b1    = (bf16*)(ws + 136314880);       //                      2097152 B
  bf16*  gi      = (bf16*)(ws + 138412032);       // ring[2][8][16][6][512]x8: 12582912 B
  bf16*  dataT   = (bf16*)(ws + 138412032);       // overlay (dead before rnn): 4 MB
  float* part    = (float*)(ws + 150994944);      // [K][T][16][B] f32:   8388608 B
  bf16*  fcW_bf  = (bf16*)(ws + 159383552);       // [K][H][F] bf16 :      262144 B
  unsigned* flags= (unsigned*)(ws + 159645696);   // [8][32] u32 = 1024 B
  unsigned* xslot= (unsigned*)(ws + 159646720);   // [8][32] u32 = 1024 B

  const int nFW = NC*Hdim*Fdim;     // 131,072
  hipLaunchKernelGGL(pack_kernel, dim3(nFW/1024), dim3(256), 0, stream, fc_in_W, fcW_bf, nFW);
  hipLaunchKernelGGL(init_kernel, dim3(4096), dim3(256), 0, stream, init_h, h_b1, flags);
  hipLaunchKernelGGL(transpose_kernel, dim3(512), dim3(256), 0, stream, data, dataT);
  hipLaunchKernelGGL(proj_kernel, dim3(8192), dim3(256), 0, stream, dataT, fcW_bf, fc_in_b, x_seq);
  hipLaunchKernelGGL(rnn_kernel, dim3(256), dim3(512), 0, stream,
      x_seq, init_h, h_b0, h_b1, Wih, Whh, bih, bhh, fc_out_W, gi, part, flags, xslot);
  hipLaunchKernelGGL(finalize_kernel, dim3(256), dim3(256), 0, stream, part, fc_out_b, out);
}

// Round 13
// 739.737 us; speedup vs baseline: 1.2212x; 1.2212x over previous
//
#include <hip/hip_runtime.h>
#include <hip/hip_bf16.h>

typedef __hip_bfloat16 bf16;
typedef __attribute__((ext_vector_type(8))) short short8;   // 8 x bf16 (4 VGPRs)
typedef __attribute__((ext_vector_type(4))) float f32x4;

#define Hdim 512
#define Bdim 512
#define Tdim 64
#define Fdim 64
#define NC   4

__device__ __forceinline__ float sigmoidf_(float x){ return 1.f/(1.f + __expf(-x)); }
__device__ __forceinline__ float tanhf_(float x){
  float t = __expf(-2.f*fabsf(x));
  float r = (1.f - t)/(1.f + t);
  return copysignf(r, x);
}
__device__ __forceinline__ float bf2f_(short u){
  return __uint_as_float(((unsigned)(unsigned short)u) << 16);
}
__device__ __forceinline__ short f2bf_(float f){
  bf16 b = (bf16)f;
  return *(short*)&b;
}

// ---------------- fp32 -> bf16 pack (fc_in_W only) ----------------
__global__ __launch_bounds__(256) void pack_kernel(const float* __restrict__ src,
                                                   bf16* __restrict__ dst, int n){
  int idx = (blockIdx.x*256 + threadIdx.x)*4;
  if (idx < n){
    float4 v = *(const float4*)(src + idx);
    dst[idx+0] = (bf16)v.x;
    dst[idx+1] = (bf16)v.y;
    dst[idx+2] = (bf16)v.z;
    dst[idx+3] = (bf16)v.w;
  }
}

// ---------------- transpose data [B][F][T] fp32 -> dataT [T][B][F] bf16 ----------------
__global__ __launch_bounds__(256) void transpose_kernel(const float* __restrict__ data,
                                                        bf16* __restrict__ dataT){
  __shared__ bf16 tile[64*65];
  int b = blockIdx.x;
  int tid = threadIdx.x;
  for (int i = 0; i < 16; ++i){
    int idx = tid + i*256;
    int f = idx >> 6, t = idx & 63;
    tile[f*65 + t] = (bf16)data[(b*64 + f)*64 + t];
  }
  __syncthreads();
  for (int i = 0; i < 16; ++i){
    int idx = tid + i*256;
    int t = idx >> 6, f = idx & 63;
    dataT[(t*Bdim + b)*64 + f] = tile[f*65 + t];
  }
}

// ---------------- init: h(-1) bf16 shadow in OWNER-MAJOR layout [k][bt][j][b][32] ----
__global__ __launch_bounds__(256) void init_kernel(const float* __restrict__ init_h,
                            bf16* __restrict__ h_b1, unsigned* __restrict__ flags){
  int idx = blockIdx.x*256 + threadIdx.x;          // 0 .. 4*512*512-1
  int k = idx >> 18;
  int rem = idx & 262143;                          // b_glob*512 + o
  int bg = rem >> 9;
  int o  = rem & 511;
  int dst = ((k*2 + (bg >> 8))*16 + (o >> 5))*8192 + (bg & 255)*32 + (o & 31);
  h_b1[dst] = (bf16)init_h[rem];
  if (idx < 512) flags[idx] = 0u;                  // flags[8][32] + xslot[8][32]
}

// ---------------- input projection: x_seq[s][k][b][h] = relu(dataT[src_t] @ fc_in_W[k]^T + b)
__global__ __launch_bounds__(256) void proj_kernel(const bf16* __restrict__ dataT,
    const bf16* __restrict__ fc_in_W, const float* __restrict__ fc_in_b,
    bf16* __restrict__ x_seq){
  __shared__ short ldsA[64*72];
  __shared__ short ldsW[128*72];
  int blk = blockIdx.x;
  int s  = blk >> 7;
  int k  = (blk >> 5) & 3;
  int bt = (blk >> 2) & 7;
  int on = blk & 3;
  int tid = threadIdx.x;
  int lane = tid & 63, wid = tid >> 6;
  int quad = lane >> 4, l16 = lane & 15;
  int src_t = (k < 2) ? s : (Tdim - 1 - s);

  const short* Ag = (const short*)(dataT + (src_t*Bdim + bt*64)*Fdim);
  #pragma unroll
  for (int i = 0; i < 2; ++i){
    int c = tid + i*256; int r = c >> 3, off = c & 7;
    *(int4*)(&ldsA[r*72 + off*8]) = *(const int4*)(&Ag[r*64 + off*8]);
  }
  const short* Wg = (const short*)(fc_in_W + (k*Hdim + on*128)*Fdim);
  #pragma unroll
  for (int i = 0; i < 4; ++i){
    int c = tid + i*256; int r = c >> 3, off = c & 7;
    *(int4*)(&ldsW[r*72 + off*8]) = *(const int4*)(&Wg[r*64 + off*8]);
  }
  __syncthreads();

  f32x4 acc[2][4];
  #pragma unroll
  for (int nt=0; nt<2; ++nt)
    #pragma unroll
    for (int rb=0; rb<4; ++rb) acc[nt][rb] = (f32x4){0.f,0.f,0.f,0.f};

  #pragma unroll
  for (int kk = 0; kk < 2; ++kk){
    int io = kk*32 + quad*8;
    short8 a[4];
    #pragma unroll
    for (int rb=0; rb<4; ++rb) a[rb] = *(const short8*)(&ldsA[(rb*16+l16)*72 + io]);
    #pragma unroll
    for (int nt=0; nt<2; ++nt){
      short8 bw = *(const short8*)(&ldsW[(wid*32 + nt*16 + l16)*72 + io]);
      #pragma unroll
      for (int rb=0; rb<4; ++rb)
        acc[nt][rb] = __builtin_amdgcn_mfma_f32_16x16x32_bf16(a[rb], bw, acc[nt][rb], 0,0,0);
    }
  }

  #pragma unroll
  for (int nt=0; nt<2; ++nt){
    int o = on*128 + wid*32 + nt*16 + l16;
    float bias = fc_in_b[k*Hdim + o];
    #pragma unroll
    for (int rb=0; rb<4; ++rb){
      #pragma unroll
      for (int reg=0; reg<4; ++reg){
        int b = bt*64 + rb*16 + quad*4 + reg;
        float v = acc[nt][rb][reg] + bias;
        v = v > 0.f ? v : 0.f;
        x_seq[((size_t)(s*NC + k)*Bdim + b)*Hdim + o] = (bf16)v;
      }
    }
  }
}

// ---------------- persistent GRU, producer/consumer split (r11 GEMM, r13 sync) ---------
// r13 vs r11: (1) gi ring depth 3 + pairwise producer<->consumer coupling: consumer j
// checks ONE producer flag (always ready with the deeper ring); producer j's WAR wait
// is consumer j only, 2 steps of slack. (2) consumer rendezvous = the 16 consumer
// flags only (the one true all-to-all dep). (3) EARLY SIGNAL: consumer bumps its flag
// right after h stores drain; the output-dot + part stores run after the bump, off
// the inter-step critical chain. GEMMs keep r11's depth-4 static prefetch (r12's
// dynamic order regressed: prefetch depth > sync slack).
__global__ __launch_bounds__(512) void rnn_kernel(
    const bf16* __restrict__ x_seq, const float* __restrict__ init_h,
    bf16* __restrict__ h_b0, bf16* __restrict__ h_b1,
    const float* __restrict__ Wih, const float* __restrict__ Whh,
    const float* __restrict__ bih, const float* __restrict__ bhh,
    const float* __restrict__ fc_out_W,
    bf16* __restrict__ gi, float* __restrict__ part,
    unsigned* __restrict__ flags, unsigned* __restrict__ xslot)
{
  __shared__ short wlds[3*2*16*512];   // 96 KB: [plane3][nt2][kc16][lane64] x 8 bf16
  __shared__ int sslot;

  int tid = threadIdx.x;
  int lane = tid & 63, wid = tid >> 6;          // wid 0..7
  int quad = lane >> 4, l16 = lane & 15;

  // ---- physical-XCD self-assignment ----
  unsigned xcc;
  asm volatile("s_getreg_b32 %0, hwreg(HW_REG_XCC_ID)" : "=s"(xcc));
  xcc &= 7u;
  if (tid == 0)
    sslot = (int)__hip_atomic_fetch_add(&xslot[xcc*32], 1u,
                __ATOMIC_RELAXED, __HIP_MEMORY_SCOPE_WORKGROUP);
  __syncthreads();
  int grp = (int)xcc;
  int k   = grp >> 1;
  int bt  = grp & 1;
  int slot = sslot & 31;               // 0..31 unique in XCD (1 block/CU pigeonhole)
  int producer = (slot < 16);
  int j    = slot & 15;                // o-tile index within role (pair id)
  int obase = j*32;
  int rot  = j;                        // K-ring phase stagger
  unsigned* gflags = flags + grp*32;   // [0..15]=producers, [16..31]=consumers

  // ---- single-side weights -> LDS once, fp32->bf16, B-fragment lane order ----
  const float* Wsrc = producer ? Wih : Whh;
  for (int i = tid; i < 3*2*16*64; i += 512){
    int plane = i >> 11;
    int rem   = i & 2047;
    int nt    = rem >> 10;
    int rem2  = rem & 1023;
    int kc    = rem2 >> 6;
    int ln    = rem2 & 63;
    int ll16  = ln & 15, lq = ln >> 4;
    const float* srcp = Wsrc +
        ((size_t)(k*3 + plane)*Hdim + obase + nt*16 + ll16)*Hdim + kc*32 + lq*8;
    float4 f0 = *(const float4*)srcp;
    float4 f1 = *(const float4*)(srcp + 4);
    short8 pk;
    pk[0]=f2bf_(f0.x); pk[1]=f2bf_(f0.y); pk[2]=f2bf_(f0.z); pk[3]=f2bf_(f0.w);
    pk[4]=f2bf_(f1.x); pk[5]=f2bf_(f1.y); pk[6]=f2bf_(f1.z); pk[7]=f2bf_(f1.w);
    *(int4*)(&wlds[i*8]) = *(int4*)&pk;
  }

  // producer GEMM over x (row stride 512): 16 K32 chunks, phase rot, depth-4 A prefetch
  #define GEMM32X(ABASE) do {                                                   \
    const short* ap0_ = (ABASE) + (wid*32 + l16)*Hdim + quad*8;                 \
    const short* ap1_ = ap0_ + 16*Hdim;                                         \
    short8 ab_[4][2];                                                           \
    _Pragma("unroll")                                                           \
    for (int d=0; d<4; ++d){                                                    \
      int c_ = (d + rot) & 15;                                                  \
      ab_[d][0] = *(const short8*)(ap0_ + c_*32);                               \
      ab_[d][1] = *(const short8*)(ap1_ + c_*32);                               \
    }                                                                           \
    short8 bb_[2][6];                                                           \
    _Pragma("unroll")                                                           \
    for (int p=0; p<6; ++p)                                                     \
      bb_[0][p] = *(const short8*)(&wlds[((p*16 + rot)<<9) + (lane<<3)]);       \
    _Pragma("unroll")                                                           \
    for (int kc=0; kc<16; ++kc){                                                \
      short8 a0_ = ab_[kc&3][0], a1_ = ab_[kc&3][1];                            \
      if (kc < 12){                                                             \
        int c_ = (kc + 4 + rot) & 15;                                           \
        ab_[kc&3][0] = *(const short8*)(ap0_ + c_*32);                          \
        ab_[kc&3][1] = *(const short8*)(ap1_ + c_*32);                          \
      }                                                                         \
      if (kc < 15){                                                             \
        int c_ = (kc + 1 + rot) & 15;                                           \
        _Pragma("unroll")                                                       \
        for (int p=0; p<6; ++p)                                                 \
          bb_[(kc+1)&1][p] = *(const short8*)(&wlds[((p*16 + c_)<<9) + (lane<<3)]); \
      }                                                                         \
      _Pragma("unroll")                                                         \
      for (int g=0; g<3; ++g){                                                  \
        _Pragma("unroll")                                                       \
        for (int nt=0; nt<2; ++nt){                                             \
          short8 bw_ = bb_[kc&1][g*2+nt];                                       \
          acc[g][nt][0] = __builtin_amdgcn_mfma_f32_16x16x32_bf16(a0_, bw_, acc[g][nt][0], 0,0,0); \
          acc[g][nt][1] = __builtin_amdgcn_mfma_f32_16x16x32_bf16(a1_, bw_, acc[g][nt][1], 0,0,0); \
        }                                                                       \
      }                                                                         \
    }                                                                           \
  } while(0)

  // consumer GEMM over h in owner-major layout: chunk c at offset c*8192 shorts
  #define GEMM32H(HCB) do {                                                     \
    const short* hp0_ = (HCB) + (wid*32 + l16)*32 + quad*8;                     \
    const short* hp1_ = hp0_ + 16*32;                                           \
    short8 ab_[4][2];                                                           \
    _Pragma("unroll")                                                           \
    for (int d=0; d<4; ++d){                                                    \
      int c_ = (d + rot) & 15;                                                  \
      ab_[d][0] = *(const short8*)(hp0_ + c_*8192);                             \
      ab_[d][1] = *(const short8*)(hp1_ + c_*8192);                             \
    }                                                                           \
    short8 bb_[2][6];                                                           \
    _Pragma("unroll")                                                           \
    for (int p=0; p<6; ++p)                                                     \
      bb_[0][p] = *(const short8*)(&wlds[((p*16 + rot)<<9) + (lane<<3)]);       \
    _Pragma("unroll")                                                           \
    for (int kc=0; kc<16; ++kc){                                                \
      short8 a0_ = ab_[kc&3][0], a1_ = ab_[kc&3][1];                            \
      if (kc < 12){                                                             \
        int c_ = (kc + 4 + rot) & 15;                                           \
        ab_[kc&3][0] = *(const short8*)(hp0_ + c_*8192);                        \
        ab_[kc&3][1] = *(const short8*)(hp1_ + c_*8192);                        \
      }                                                                         \
      if (kc < 15){                                                             \
        int c_ = (kc + 1 + rot) & 15;                                           \
        _Pragma("unroll")                                                       \
        for (int p=0; p<6; ++p)                                                 \
          bb_[(kc+1)&1][p] = *(const short8*)(&wlds[((p*16 + c_)<<9) + (lane<<3)]); \
      }                                                                         \
      _Pragma("unroll")                                                         \
      for (int g=0; g<3; ++g){                                                  \
        _Pragma("unroll")                                                       \
        for (int nt=0; nt<2; ++nt){                                             \
          short8 bw_ = bb_[kc&1][g*2+nt];                                       \
          acc[g][nt][0] = __builtin_amdgcn_mfma_f32_16x16x32_bf16(a0_, bw_, acc[g][nt][0], 0,0,0); \
          acc[g][nt][1] = __builtin_amdgcn_mfma_f32_16x16x32_bf16(a1_, bw_, acc[g][nt][1], 0,0,0); \
        }                                                                       \
      }                                                                         \
    }                                                                           \
  } while(0)

  if (producer){
    __syncthreads();   // LDS fill complete
    for (int s = 0; s < 64; ++s){
      f32x4 acc[3][2][2];
      #pragma unroll
      for (int g=0; g<3; ++g)
        #pragma unroll
        for (int nt=0; nt<2; ++nt){
          acc[g][nt][0] = (f32x4){0.f,0.f,0.f,0.f};
          acc[g][nt][1] = (f32x4){0.f,0.f,0.f,0.f};
        }
      // ring WAR (depth 3): only pair consumer j reads gi block j
      if (s >= 3){
        if (wid == 0){
          int g_ = 0;
          while (__hip_atomic_load(&gflags[16 + j], __ATOMIC_RELAXED,
                                   __HIP_MEMORY_SCOPE_AGENT) < (unsigned)(s - 2)){
            __builtin_amdgcn_s_sleep(1);
            if (++g_ > 4000000) break;
          }
        }
        __syncthreads();
      }
      const short* x_base = (const short*)(x_seq + ((size_t)(s*NC + k)*Bdim + bt*256)*Hdim);
      GEMM32X(x_base);
      bf16* gb = gi + ((size_t)(((s % 3)*8 + grp)*16 + j))*24576;
      #pragma unroll
      for (int g=0; g<3; ++g){
        #pragma unroll
        for (int nt=0; nt<2; ++nt){
          short8 pk;
          #pragma unroll
          for (int rb=0; rb<2; ++rb)
            #pragma unroll
            for (int reg=0; reg<4; ++reg)
              pk[rb*4+reg] = f2bf_(acc[g][nt][rb][reg]);
          *(int4*)(gb + ((g*2+nt)*512 + wid*64 + lane)*8) = *(int4*)&pk;
        }
      }
      __syncthreads();                     // drains vmcnt(0): gi visible in local L2
      if (tid == 0)
        __hip_atomic_fetch_add(&gflags[j], 1u,
                               __ATOMIC_RELAXED, __HIP_MEMORY_SCOPE_AGENT);
    }
  } else {
    // ---- consumer: biases, output weights, fp32 h state in registers ----
    int o0 = obase + l16, o1 = o0 + 16;
    float br0  = bih[k*3*Hdim + o0] + bhh[k*3*Hdim + o0];
    float br1  = bih[k*3*Hdim + o1] + bhh[k*3*Hdim + o1];
    float bz0  = bih[k*3*Hdim + Hdim + o0] + bhh[k*3*Hdim + Hdim + o0];
    float bz1  = bih[k*3*Hdim + Hdim + o1] + bhh[k*3*Hdim + Hdim + o1];
    float bnx0 = bih[k*3*Hdim + 2*Hdim + o0];
    float bnx1 = bih[k*3*Hdim + 2*Hdim + o1];
    float bnh0 = bhh[k*3*Hdim + 2*Hdim + o0];
    float bnh1 = bhh[k*3*Hdim + 2*Hdim + o1];
    float wout0 = fc_out_W[(k & 1)*Hdim + o0];
    float wout1 = fc_out_W[(k & 1)*Hdim + o1];

    float hk[2][2][4];   // [nt][rb][reg]
    #pragma unroll
    for (int nt=0; nt<2; ++nt)
      #pragma unroll
      for (int rb=0; rb<2; ++rb)
        #pragma unroll
        for (int reg=0; reg<4; ++reg)
          hk[nt][rb][reg] =
            init_h[(bt*256 + wid*32 + rb*16 + quad*4 + reg)*Hdim + obase + nt*16 + l16];

    __syncthreads();   // LDS fill complete

    const int hgrp = (k*2 + bt)*16;    // h block base index for this group

    for (int s = 0; s < 64; ++s){
      const bf16* h_in  = (s & 1) ? h_b0 : h_b1;
      bf16*       h_out = (s & 1) ? h_b1 : h_b0;

      f32x4 acc[3][2][2];
      #pragma unroll
      for (int g=0; g<3; ++g)
        #pragma unroll
        for (int nt=0; nt<2; ++nt){
          acc[g][nt][0] = (f32x4){0.f,0.f,0.f,0.f};
          acc[g][nt][1] = (f32x4){0.f,0.f,0.f,0.f};
        }

      // rendezvous: 16 consumer flags >= s (the one true all-to-all dep) + pair
      // producer flag >= s+1 (lane 16; near-always ready with the depth-3 ring)
      {
        if (wid == 0){
          int g_ = 0;
          for (;;){
            unsigned v_ = 0xFFFFFFFFu, thr_ = 0u;
            if (lane < 16){
              v_ = __hip_atomic_load(&gflags[16 + lane], __ATOMIC_RELAXED,
                                     __HIP_MEMORY_SCOPE_AGENT);
              thr_ = (unsigned)s;
            } else if (lane == 16){
              v_ = __hip_atomic_load(&gflags[j], __ATOMIC_RELAXED,
                                     __HIP_MEMORY_SCOPE_AGENT);
              thr_ = (unsigned)(s + 1);
            }
            if (__ballot(v_ >= thr_) == ~0ull) break;
            __builtin_amdgcn_s_sleep(1);
            if (++g_ > 4000000) break;
          }
        }
        __syncthreads();
      }

      // gi prefetch first (latency hides under the h-GEMM)
      const bf16* gb = gi + ((size_t)(((s % 3)*8 + grp)*16 + j))*24576;
      short8 gv[6];
      #pragma unroll
      for (int p=0; p<6; ++p){
        int4 t = *(const int4*)(gb + (p*512 + wid*64 + lane)*8);
        gv[p] = *(short8*)&t;
      }

      const short* h_cb = (const short*)h_in + (size_t)hgrp*8192;
      GEMM32H(h_cb);

      // ---- critical-path epilogue: gates, register h update, h store ONLY ----
      float hnv[2][2][4];
      bf16* hob = h_out + (size_t)(hgrp + j)*8192;
      #pragma unroll
      for (int rb = 0; rb < 2; ++rb){
        #pragma unroll
        for (int reg = 0; reg < 4; ++reg){
          int bl = wid*32 + rb*16 + quad*4 + reg;     // local b row
          #pragma unroll
          for (int nt = 0; nt < 2; ++nt){
            float gir = bf2f_(gv[0*2+nt][rb*4+reg]);
            float giz = bf2f_(gv[1*2+nt][rb*4+reg]);
            float gin = bf2f_(gv[2*2+nt][rb*4+reg]);
            float br  = nt ? br1 : br0,  bz = nt ? bz1 : bz0;
            float bnx = nt ? bnx1 : bnx0, bnh = nt ? bnh1 : bnh0;
            float r = sigmoidf_(gir + acc[0][nt][rb][reg] + br);
            float z = sigmoidf_(giz + acc[1][nt][rb][reg] + bz);
            float n = tanhf_(gin + bnx + r*(acc[2][nt][rb][reg] + bnh));
            float hn = (1.f - z)*n + z*hk[nt][rb][reg];
            hk[nt][rb][reg] = hn;
            hnv[nt][rb][reg] = hn;
            hob[bl*32 + nt*16 + l16] = (bf16)hn;
          }
        }
      }

      // ---- EARLY SIGNAL: drain h stores, bump flag; part dots run after ----
      __syncthreads();                   // drains vmcnt(0): h in local L2
      if (tid == 0)
        __hip_atomic_fetch_add(&gflags[16 + j], 1u,
                               __ATOMIC_RELAXED, __HIP_MEMORY_SCOPE_AGENT);

      // ---- off-critical-path: output head dot + nontemporal part store ----
      int tmap = (k < 2) ? s : (Tdim - 1 - s);
      #pragma unroll
      for (int rb = 0; rb < 2; ++rb){
        #pragma unroll
        for (int reg = 0; reg < 4; ++reg){
          int bl = wid*32 + rb*16 + quad*4 + reg;
          float v = hnv[0][rb][reg]*wout0 + hnv[1][rb][reg]*wout1;
          v += __shfl_xor(v, 1, 64);
          v += __shfl_xor(v, 2, 64);
          v += __shfl_xor(v, 4, 64);
          v += __shfl_xor(v, 8, 64);
          if (l16 == 0)
            __builtin_nontemporal_store(v,
              &part[((size_t)(k*Tdim + tmap)*16 + j)*Bdim + bt*256 + bl]);
        }
      }
    }
  }
  #undef GEMM32X
  #undef GEMM32H
}

// ---------------- out[head][b][t] = bias + sum over {head,head+2} x 16 j-partials ----
__global__ __launch_bounds__(256) void finalize_kernel(const float* __restrict__ part,
                                const float* __restrict__ fc_out_b, float* __restrict__ out){
  int idx = blockIdx.x*256 + threadIdx.x;  // 0..65535
  int head = idx >> 15;
  int b = (idx >> 6) & 511;
  int t = idx & 63;
  float v = fc_out_b[head];
  #pragma unroll
  for (int kk = 0; kk < 2; ++kk){
    const float* p = part + (size_t)((head + kk*2)*Tdim + t)*16*Bdim + b;
    #pragma unroll
    for (int jj = 0; jj < 16; ++jj)
      v += p[jj*Bdim];
  }
  out[idx] = v;
}

extern "C" void kernel_launch(void* const* d_in, const int* in_sizes, int n_in,
                              void* d_out, int out_size, void* d_ws, size_t ws_size,
                              hipStream_t stream){
  (void)in_sizes; (void)n_in; (void)out_size; (void)ws_size;
  const float* data     = (const float*)d_in[0];
  const float* init_h   = (const float*)d_in[1];
  const float* fc_in_W  = (const float*)d_in[2];
  const float* fc_in_b  = (const float*)d_in[3];
  const float* Wih      = (const float*)d_in[4];
  const float* Whh      = (const float*)d_in[5];
  const float* bih      = (const float*)d_in[6];
  const float* bhh      = (const float*)d_in[7];
  const float* fc_out_W = (const float*)d_in[8];
  const float* fc_out_b = (const float*)d_in[9];
  float* out = (float*)d_out;

  char* ws = (char*)d_ws;
  bf16*  x_seq   = (bf16*)ws;                     // [T][K][B][H] bf16 : 134217728 B
  bf16*  h_b0    = (bf16*)(ws + 134217728);       // [k][bt][j][b][32] :  2097152 B
  bf16*  h_b1    = (bf16*)(ws + 136314880);       //                      2097152 B
  bf16*  gi      = (bf16*)(ws + 138412032);       // ring[3][8][16][6][512]x8: 18874368 B
  bf16*  dataT   = (bf16*)(ws + 138412032);       // overlay (dead before rnn): 4 MB
  float* part    = (float*)(ws + 157286400);      // [K][T][16][B] f32:   8388608 B
  bf16*  fcW_bf  = (bf16*)(ws + 165675008);       // [K][H][F] bf16 :      262144 B
  unsigned* flags= (unsigned*)(ws + 165937152);   // [8][32] u32 = 1024 B
  unsigned* xslot= (unsigned*)(ws + 165938176);   // [8][32] u32 = 1024 B

  const int nFW = NC*Hdim*Fdim;     // 131,072
  hipLaunchKernelGGL(pack_kernel, dim3(nFW/1024), dim3(256), 0, stream, fc_in_W, fcW_bf, nFW);
  hipLaunchKernelGGL(init_kernel, dim3(4096), dim3(256), 0, stream, init_h, h_b1, flags);
  hipLaunchKernelGGL(transpose_kernel, dim3(512), dim3(256), 0, stream, data, dataT);
  hipLaunchKernelGGL(proj_kernel, dim3(8192), dim3(256), 0, stream, dataT, fcW_bf, fc_in_b, x_seq);
  hipLaunchKernelGGL(rnn_kernel, dim3(256), dim3(512), 0, stream,
      x_seq, init_h, h_b0, h_b1, Wih, Whh, bih, bhh, fc_out_W, gi, part, flags, xslot);
  hipLaunchKernelGGL(finalize_kernel, dim3(256), dim3(256), 0, stream, part, fc_out_b, out);
}